// Round 3
// baseline (265.212 us; speedup 1.0000x reference)
//
#include <hip/hip_runtime.h>

#define G 4096
#define BSZ 2
#define NIN 8
#define HID 32

typedef __attribute__((ext_vector_type(8))) short short8;
typedef __attribute__((ext_vector_type(4))) float floatx4;
typedef __attribute__((ext_vector_type(2))) short short2v;
typedef __attribute__((ext_vector_type(4))) short short4v;
typedef unsigned short ushort_t;

__device__ __forceinline__ float elu1(float v) {
    return v > 0.f ? v : (__expf(v) - 1.f);
}
__device__ __forceinline__ ushort_t f2bf(float f) {
    unsigned u = __float_as_uint(f);
    u += 0x7fffu + ((u >> 16) & 1u);
    return (ushort_t)(u >> 16);
}

// h = elu(x@W_infer+b); s_src/s_dst projections; hT bf16 [b][c][g]
__global__ void k_setup1(const float* __restrict__ x, const float* __restrict__ W,
                         const float* __restrict__ bias, const float* __restrict__ We,
                         float* __restrict__ h0, ushort_t* __restrict__ hTb,
                         float* __restrict__ ssrc, float* __restrict__ sdst) {
    int t = blockIdx.x * blockDim.x + threadIdx.x;
    if (t >= BSZ * G) return;
    int b = t >> 12, g = t & (G - 1);
    float xin[NIN];
    const float* xp = x + t * NIN;
#pragma unroll
    for (int k = 0; k < NIN; k++) xin[k] = xp[k];
    float ss = 0.f, sd = 0.f;
    float* hp = h0 + (size_t)t * HID;
#pragma unroll
    for (int o = 0; o < HID; o++) {
        float v = bias[o];
#pragma unroll
        for (int k = 0; k < NIN; k++) v += xin[k] * W[k * HID + o];
        v = elu1(v);
        hp[o] = v;
        hTb[(size_t)(b * HID + o) * G + g] = f2bf(v);  // coalesced over g
        ss += v * We[o];
        sd += v * We[HID + o];
    }
    ssrc[t] = ss;
    sdst[t] = sd;
}

// MFMA aggregation, no LDS/barriers, ping-pong prefetch of adj + hT fragments.
// Wave w: b=w>>1, ihalf=w&1. A-frag e: lane l = (m=l&15, k=(l>>4)*8+t).
__global__ __launch_bounds__(256) void k_main(
    const float* __restrict__ adj, const float* __restrict__ ssrc,
    const float* __restrict__ sdst, const ushort_t* __restrict__ hTb,
    const float* __restrict__ bep, float coef, float* __restrict__ part,
    int chunk) {
    int tid = threadIdx.x;
    int w = tid >> 6, l = tid & 63;
    int b = w >> 1, ihalf = w & 1;
    int i0 = blockIdx.x * 32;
    int i = i0 + ihalf * 16 + (l & 15);
    int kg = l >> 4;
    int jbase = blockIdx.y * chunk;
    float sd = sdst[b * G + i] + bep[0];
    float wm1 = 1.f - coef;
    const float* adjrow = adj + (size_t)i * G + jbase + kg * 8;
    const float* srow = ssrc + b * G + jbase + kg * 8;
    const ushort_t* hb0 = hTb + (size_t)(b * HID + (l & 15)) * G + jbase + kg * 8;
    const ushort_t* hb1 = hb0 + (size_t)16 * G;
    floatx4 c0 = {0.f, 0.f, 0.f, 0.f}, c1 = {0.f, 0.f, 0.f, 0.f};
    float es = 0.f;
    int iters = chunk >> 5;

    float4 pa0 = *(const float4*)(adjrow);
    float4 pa1 = *(const float4*)(adjrow + 4);
    short8 pb0 = *(const short8*)(const void*)(hb0);
    short8 pb1 = *(const short8*)(const void*)(hb1);

    for (int jc = 0; jc < iters; jc++) {
        float4 a0 = pa0, a1 = pa1;
        short8 bf0 = pb0, bf1 = pb1;
        if (jc + 1 < iters) {
            int o = (jc + 1) * 32;
            pa0 = *(const float4*)(adjrow + o);
            pa1 = *(const float4*)(adjrow + o + 4);
            pb0 = *(const short8*)(const void*)(hb0 + o);
            pb1 = *(const short8*)(const void*)(hb1 + o);
        }
        float4 s0 = *(const float4*)(srow + jc * 32);
        float4 s1 = *(const float4*)(srow + jc * 32 + 4);
        float av[8] = {a0.x, a0.y, a0.z, a0.w, a1.x, a1.y, a1.z, a1.w};
        float sv[8] = {s0.x, s0.y, s0.z, s0.w, s1.x, s1.y, s1.z, s1.w};
        short8 af;
#pragma unroll
        for (int t = 0; t < 8; t++) {
            float wgt = __builtin_fmaf(av[t], wm1, coef);  // exact for adj in {0,1}
            float sg = __builtin_amdgcn_rcpf(1.f + __expf(-(sd + sv[t])));
            float e = sg * wgt;
            es += e;
            af[t] = (short)f2bf(e);
        }
        c0 = __builtin_amdgcn_mfma_f32_16x16x32_bf16(af, bf0, c0, 0, 0, 0);
        c1 = __builtin_amdgcn_mfma_f32_16x16x32_bf16(af, bf1, c1, 0, 0, 0);
    }
    es += __shfl_xor(es, 16);
    es += __shfl_xor(es, 32);
    size_t rb = ((size_t)(blockIdx.y * BSZ + b)) * G;
#pragma unroll
    for (int r = 0; r < 4; r++) {
        int row = i0 + ihalf * 16 + kg * 4 + r;  // C/D: row=(l>>4)*4+reg, col=l&15
        part[(rb + row) * 33 + (l & 15)] = c0[r];
        part[(rb + row) * 33 + 16 + (l & 15)] = c1[r];
    }
    if (l < 16) part[(rb + i) * 33 + 32] = es;
}

// Reduce partials; node+merge MLPs; optional fused BN + We2 proj + hT write.
// 4 genes (8 rows) per block; wave = 2 rows = one gene's (b=0,b=1).
template <bool DO_BN>
__global__ __launch_bounds__(256) void k_post(
    const float* __restrict__ part, const float* __restrict__ hin,
    const float* __restrict__ Wn, const float* __restrict__ bnb,
    const float* __restrict__ Wm, const float* __restrict__ bmb,
    const float* __restrict__ gamma, const float* __restrict__ beta,
    const float* __restrict__ We2, float* __restrict__ outp,
    ushort_t* __restrict__ hTb, float* __restrict__ s2s,
    float* __restrict__ s2d, int jsn) {
    __shared__ float Wns[64 * 32];
    __shared__ float Wms[64 * 32];
    __shared__ float rec[8][68];
    __shared__ float rec2[8][68];
    __shared__ ushort_t tb[BSZ][HID][4];
    int tid = threadIdx.x;
    int rl = tid >> 5, hh = tid & 31;
#pragma unroll
    for (int r = 0; r < 8; r++) {
        Wns[r * 256 + tid] = Wn[r * 256 + tid];
        Wms[r * 256 + tid] = Wm[r * 256 + tid];
    }
    int g0 = blockIdx.x * 4;
    int b = rl & 1;
    int g = g0 + (rl >> 1);
    int rowf = b * G + g;
    float rs = 0.f, es = 0.f;
    for (int js = 0; js < jsn; js++) {
        size_t base = ((size_t)(js * BSZ + b) * G + g) * 33;
        rs += part[base + hh];
        es += part[base + 32];
    }
    float xv = hin[(size_t)rowf * HID + hh];
    rec[rl][hh] = rs;
    rec[rl][32 + hh] = xv * es;
    __syncthreads();
    float v = bnb[hh];
#pragma unroll
    for (int k4 = 0; k4 < 16; k4++) {
        float4 r4 = *(const float4*)&rec[rl][k4 * 4];
        v += r4.x * Wns[(k4 * 4 + 0) * HID + hh];
        v += r4.y * Wns[(k4 * 4 + 1) * HID + hh];
        v += r4.z * Wns[(k4 * 4 + 2) * HID + hh];
        v += r4.w * Wns[(k4 * 4 + 3) * HID + hh];
    }
    v = elu1(v);
    rec2[rl][hh] = v;
    rec2[rl][32 + hh] = xv;
    __syncthreads();
    float u = bmb[hh];
#pragma unroll
    for (int k4 = 0; k4 < 16; k4++) {
        float4 r4 = *(const float4*)&rec2[rl][k4 * 4];
        u += r4.x * Wms[(k4 * 4 + 0) * HID + hh];
        u += r4.y * Wms[(k4 * 4 + 1) * HID + hh];
        u += r4.z * Wms[(k4 * 4 + 2) * HID + hh];
        u += r4.w * Wms[(k4 * 4 + 3) * HID + hh];
    }
    float h1v = elu1(u);
    if (!DO_BN) {
        outp[(size_t)rowf * HID + hh] = h1v;
    } else {
        // wave = gene g's 64 values (b = lane>>5, feature = lane&31)
        float s = h1v, sq = h1v * h1v;
#pragma unroll
        for (int m = 32; m; m >>= 1) {
            s += __shfl_xor(s, m);
            sq += __shfl_xor(sq, m);
        }
        float mu = s * (1.f / 64.f);
        float var = sq * (1.f / 64.f) - mu * mu;
        float rstd = rsqrtf(var + 1e-5f);
        float hn = (h1v - mu) * rstd * gamma[g] + beta[g];
        outp[(size_t)rowf * HID + hh] = hn;
        tb[b][hh][rl >> 1] = f2bf(hn);
        float ps = hn * We2[hh], pd = hn * We2[HID + hh];
#pragma unroll
        for (int m = 16; m; m >>= 1) {
            ps += __shfl_xor(ps, m);
            pd += __shfl_xor(pd, m);
        }
        if (hh == 0) {
            s2s[rowf] = ps;
            s2d[rowf] = pd;
        }
        __syncthreads();
        if (tid < 64) {
            int b2 = tid >> 5, c = tid & 31;
            short4v val = *(const short4v*)&tb[b2][c][0];
            *(short4v*)(void*)&hTb[(size_t)(b2 * HID + c) * G + g0] = val;
        }
    }
}

extern "C" void kernel_launch(void* const* d_in, const int* in_sizes, int n_in,
                              void* d_out, int out_size, void* d_ws, size_t ws_size,
                              hipStream_t stream) {
    const float* x      = (const float*)d_in[0];
    const float* edges1 = (const float*)d_in[1];
    const float* edges2 = (const float*)d_in[2];
    const float* W_inf  = (const float*)d_in[3];
    const float* b_inf  = (const float*)d_in[4];
    const float* W_e1   = (const float*)d_in[5];
    const float* b_e1   = (const float*)d_in[6];
    const float* W_e2   = (const float*)d_in[7];
    const float* b_e2   = (const float*)d_in[8];
    const float* W_n1   = (const float*)d_in[9];
    const float* b_n1   = (const float*)d_in[10];
    const float* W_n2   = (const float*)d_in[11];
    const float* b_n2   = (const float*)d_in[12];
    const float* W_m1   = (const float*)d_in[13];
    const float* b_m1   = (const float*)d_in[14];
    const float* W_m2   = (const float*)d_in[15];
    const float* b_m2   = (const float*)d_in[16];
    const float* bn_g   = (const float*)d_in[17];
    const float* bn_b   = (const float*)d_in[18];
    float* out = (float*)d_out;

    float* ws = (float*)d_ws;
    float* h0   = ws;                        // 262144
    float* h1n  = ws + 262144;               // 262144
    float* s1s  = ws + 524288;               // 8192
    float* s1d  = ws + 532480;               // 8192
    float* s2s  = ws + 540672;               // 8192
    float* s2d  = ws + 548864;               // 8192
    float* part = ws + 557056;

    // 16 j-slices if workspace allows, else 8 (round-2 footprint)
    int JSN = 16;
    size_t need16 = ((size_t)557056 + (size_t)16 * BSZ * G * 33 + 131072) * 4;
    if (ws_size < need16) JSN = 8;
    int chunk = G / JSN;
    ushort_t* hTb = (ushort_t*)(part + (size_t)JSN * BSZ * G * 33);

    const float ALPHA = 0.005f, BETA = 5e-5f;

    k_setup1<<<32, 256, 0, stream>>>(x, W_inf, b_inf, W_e1, h0, hTb, s1s, s1d);
    k_main<<<dim3(G / 32, JSN), 256, 0, stream>>>(edges1, s1s, s1d, hTb, b_e1, ALPHA,
                                                  part, chunk);
    k_post<true><<<G / 4, 256, 0, stream>>>(part, h0, W_n1, b_n1, W_m1, b_m1,
                                            bn_g, bn_b, W_e2, h1n, hTb, s2s, s2d, JSN);
    k_main<<<dim3(G / 32, JSN), 256, 0, stream>>>(edges2, s2s, s2d, hTb, b_e2, BETA,
                                                  part, chunk);
    k_post<false><<<G / 4, 256, 0, stream>>>(part, h1n, W_n2, b_n2, W_m2, b_m2,
                                             nullptr, nullptr, nullptr, out,
                                             nullptr, nullptr, nullptr, JSN);
}